// Round 7
// baseline (81.442 us; speedup 1.0000x reference)
//
#include <hip/hip_runtime.h>

// ApproxNDCGLoss, N=20000, fp32 — TWO dispatches; privatized 2-level sort.
//
// R6 post-mortem: total 80.76 = 39.5 (unavoidable 256MiB ws-poison fill)
// + ~41.3 kernel-side. Cross-round split: produce(sort-only blk0) ~16 us,
// consume ~8-12, dispatch gaps ~12-16. Produce's pole is block 0: 20k LDS
// hist atomics + 20k LDS cursor atomics, 16 waves on ONE hist copy.
//
// R7 change (only): privatized counting sort in block 0 —
//   - 4 wave-group-private LDS histograms h4[4][2048] (32 KB): hist pass
//     contention /4.
//   - scan computes per-group exclusive starts; each group scatters through
//     its PRIVATE cursor: scatter contention /4. Within-bucket order changes
//     (group-major) but the per-bucket multiset is identical => exact ranks
//     unchanged => absmax stays 0.0.
// Everything else (node blocks, consume, finalize) byte-identical to R6
// (verified absmax 0.0).
//
// Decision rule: if total moves <2 us, kernel side is gap-dominated =>
// structure is at its floor (fill + 2 minimal kernels + graph overhead).

#define LOG2E 1.442695040888963387f
#define M_NODES 64
#define XHALF 8.0
#define NB 2048
#define PI_D 3.14159265358979323846
#define BT 1024
#define MAXN 131072

#if __has_builtin(__builtin_amdgcn_exp2f)
#define EXP2(x) __builtin_amdgcn_exp2f(x)
#else
#define EXP2(x) exp2f(x)
#endif

#if __has_builtin(__builtin_amdgcn_rcpf)
#define RCP(x) __builtin_amdgcn_rcpf(x)
#else
#define RCP(x) (1.0f / (x))
#endif

// ---- module-global state (poison-free; visibility via kernel boundary) ----
__device__ double g_acc[3] = {0.0, 0.0, 0.0};  // dcg, idcg, ysum
__device__ int g_done = 0;
__device__ float2 g_nodes[M_NODES];  // (x_k, F_k)
__device__ int g_prefix[NB + 1];     // bucket starts
__device__ float g_ybkt[MAXN];       // bucket-sorted y

__device__ __forceinline__ int bucket_of(float y) {
  int b = (int)(y * (float)NB);
  return b < 0 ? 0 : (b > NB - 1 ? NB - 1 : b);
}

// ---- produce: blk 0 = privatized counting sort; blk 1..64 = nodes ----
__global__ __launch_bounds__(BT) void produce_kernel(
    const float* __restrict__ s, const float* __restrict__ y, int n) {
  const int tid = threadIdx.x;
  const int blk = blockIdx.x;
  const int lane = tid & 63;

  __shared__ int h4[4][NB];    // 4 group-private hists, then cursors (32 KB)
  __shared__ int wrep[16];     // scan wave partials
  __shared__ double wsum[16];  // node reduction scratch

  if (blk == 0) {
    // --- zero the 4 private histograms ---
    for (int i = tid; i < 4 * NB; i += BT) ((int*)h4)[i] = 0;
    __syncthreads();

    const int g = tid >> 8;  // wave-group 0..3 (each wave wholly in a group)
    const float4* y4 = (const float4*)y;
    const int n4 = n >> 2;

    // --- histogram pass (group-private => contention /4) ---
    for (int i = tid; i < n4; i += BT) {
      const float4 v = y4[i];
      atomicAdd(&h4[g][bucket_of(v.x)], 1);
      atomicAdd(&h4[g][bucket_of(v.y)], 1);
      atomicAdd(&h4[g][bucket_of(v.z)], 1);
      atomicAdd(&h4[g][bucket_of(v.w)], 1);
    }
    for (int i = (n4 << 2) + tid; i < n; i += BT)
      atomicAdd(&h4[g][bucket_of(y[i])], 1);
    __syncthreads();

    // --- merge + exclusive scan (2 buckets/thread), shuffle, 2 barriers ---
    const int base = tid * 2;
    const int c00 = h4[0][base], c10 = h4[1][base];
    const int c20 = h4[2][base], c30 = h4[3][base];
    const int c01 = h4[0][base + 1], c11 = h4[1][base + 1];
    const int c21 = h4[2][base + 1], c31 = h4[3][base + 1];
    const int l0 = c00 + c10 + c20 + c30;
    const int l1 = c01 + c11 + c21 + c31;
    const int sum2 = l0 + l1;
    int v = sum2;
#pragma unroll
    for (int d = 1; d < 64; d <<= 1) {
      const int t = __shfl_up(v, d);
      if (lane >= d) v += t;
    }
    if (lane == 63) wrep[tid >> 6] = v;
    __syncthreads();
    if (tid < 16) {
      int wv = wrep[tid];
#pragma unroll
      for (int d = 1; d < 16; d <<= 1) {
        const int t = __shfl_up(wv, d);
        if (tid >= d) wv += t;
      }
      wrep[tid] = wv;
    }
    __syncthreads();
    const int wbase = (tid >> 6) ? wrep[(tid >> 6) - 1] : 0;
    const int incl = wbase + v;
    const int run = incl - sum2;  // exclusive start of bucket `base`
    g_prefix[base] = run;         // publish (boundary makes it visible)
    g_prefix[base + 1] = run + l0;
    if (tid == BT - 1) g_prefix[NB] = incl;  // == n

    // per-group private scatter cursors (group-major within each bucket)
    h4[0][base] = run;
    h4[1][base] = run + c00;
    h4[2][base] = run + c00 + c10;
    h4[3][base] = run + c00 + c10 + c20;
    h4[0][base + 1] = run + l0;
    h4[1][base + 1] = run + l0 + c01;
    h4[2][base + 1] = run + l0 + c01 + c11;
    h4[3][base + 1] = run + l0 + c01 + c11 + c21;
    __syncthreads();

    // --- scatter (same group partition => private cursors are exact) ---
    for (int i = tid; i < n4; i += BT) {
      const float4 v4 = y4[i];
      g_ybkt[atomicAdd(&h4[g][bucket_of(v4.x)], 1)] = v4.x;
      g_ybkt[atomicAdd(&h4[g][bucket_of(v4.y)], 1)] = v4.y;
      g_ybkt[atomicAdd(&h4[g][bucket_of(v4.z)], 1)] = v4.z;
      g_ybkt[atomicAdd(&h4[g][bucket_of(v4.w)], 1)] = v4.w;
    }
    for (int i = (n4 << 2) + tid; i < n; i += BT) {
      const float yv = y[i];
      g_ybkt[atomicAdd(&h4[g][bucket_of(yv)], 1)] = yv;
    }
  } else {
    // --- node k: F(x_k) = sum_i sigmoid(x_k - s_i) (verified math) ---
    const int k = blk - 1;
    const float xk =
        (float)(XHALF * cos(PI_D * (double)k / (double)(M_NODES - 1)));
    double F = 0.0;
    const float4* s4 = (const float4*)s;
    const int n4 = n >> 2;
    for (int i = tid; i < n4; i += BT) {
      const float4 v = s4[i];
      float t = RCP(1.0f + EXP2((v.x - xk) * LOG2E));
      t += RCP(1.0f + EXP2((v.y - xk) * LOG2E));
      t += RCP(1.0f + EXP2((v.z - xk) * LOG2E));
      t += RCP(1.0f + EXP2((v.w - xk) * LOG2E));
      F += (double)t;
    }
    for (int i = (n4 << 2) + tid; i < n; i += BT)
      F += (double)RCP(1.0f + EXP2((s[i] - xk) * LOG2E));
    for (int off = 32; off > 0; off >>= 1) F += __shfl_down(F, off);
    if (lane == 0) wsum[tid >> 6] = F;
    __syncthreads();
    if (tid == 0) {
      double t = 0.0;
#pragma unroll
      for (int w = 0; w < 16; ++w) t += wsum[w];
      g_nodes[k] = make_float2(xk, (float)t);
    }
  }
}

// ---- consume: barycentric dcg + parallel rank-scan idcg + finalize ----
__global__ __launch_bounds__(256) void consume_kernel(
    const float* __restrict__ s, const float* __restrict__ y,
    float* __restrict__ out, int n, int nblocks) {
  __shared__ float2 nd[M_NODES];
  __shared__ double wsum[12];
  const int tid = threadIdx.x;
  if (tid < M_NODES) nd[tid] = g_nodes[tid];
  __syncthreads();

  const int j = blockIdx.x * 256 + tid;
  double dc = 0.0, ic = 0.0, ys = 0.0;
  if (j < n) {
    const float x = s[j];
    const float yj = y[j];
    // dcg: barycentric interpolation of F(s_j) over 64 Chebyshev nodes
    double num = 0.0, den = 0.0;
    int hit = -1;
#pragma unroll
    for (int k = 0; k < M_NODES; ++k) {
      const float d = x - nd[k].x;
      float w = (k & 1) ? -1.0f : 1.0f;
      if (k == 0 || k == M_NODES - 1) w *= 0.5f;
      if (d == 0.0f) {
        hit = k;
      } else {
        const float iv = w * RCP(d);
        num += (double)iv * (double)nd[k].y;
        den += (double)iv;
      }
    }
    const double F = (hit >= 0) ? (double)nd[hit].y : (num / den);

    // idcg: exact rank = 1 + #(strictly greater); L2-resident bucket scan
    const int b = bucket_of(yj);
    const int s0 = g_prefix[b];
    const int s1 = g_prefix[b + 1];
    int cnt = n - s1;  // strictly higher buckets
    for (int t = s0; t < s1; ++t) cnt += (g_ybkt[t] > yj);

    dc = (double)yj / log2(F + 2.0);
    ic = (double)yj / log2((double)cnt + 2.0);
    ys = (double)yj;
  }
  for (int off = 32; off > 0; off >>= 1) {
    dc += __shfl_down(dc, off);
    ic += __shfl_down(ic, off);
    ys += __shfl_down(ys, off);
  }
  const int wv = tid >> 6;
  if ((tid & 63) == 0) {
    wsum[wv] = dc;
    wsum[wv + 4] = ic;
    wsum[wv + 8] = ys;
  }
  __syncthreads();
  if (tid == 0) {
    atomicAdd(&g_acc[0], wsum[0] + wsum[1] + wsum[2] + wsum[3]);
    atomicAdd(&g_acc[1], wsum[4] + wsum[5] + wsum[6] + wsum[7]);
    atomicAdd(&g_acc[2], wsum[8] + wsum[9] + wsum[10] + wsum[11]);
    __threadfence();
    const int old = atomicAdd(&g_done, 1);
    if (old == nblocks - 1) {  // last block: all acc updates visible
      const double dcg = atomicAdd(&g_acc[0], 0.0);
      const double idcg = atomicAdd(&g_acc[1], 0.0);
      const double ysum = atomicAdd(&g_acc[2], 0.0);
      const double loss = 1.0 - dcg / (idcg + 1e-8);
      out[0] = (ysum < 1.0) ? 0.0f : (float)loss;
      // self-clean for next replay (visible via kernel boundary)
      g_acc[0] = 0.0;
      g_acc[1] = 0.0;
      g_acc[2] = 0.0;
      g_done = 0;
      __threadfence();
    }
  }
}

extern "C" void kernel_launch(void* const* d_in, const int* in_sizes, int n_in,
                              void* d_out, int out_size, void* d_ws,
                              size_t ws_size, hipStream_t stream) {
  const float* s = (const float*)d_in[0];
  const float* y = (const float*)d_in[1];
  const int n = in_sizes[0];
  (void)d_ws;
  (void)ws_size;  // ws poison is unconditional; module globals are poison-free

  const int nb = (n + 255) / 256;
  produce_kernel<<<M_NODES + 1, BT, 0, stream>>>(s, y, n);
  consume_kernel<<<nb, 256, 0, stream>>>(s, y, (float*)d_out, n, nb);
}

// Round 8
// 73.913 us; speedup vs baseline: 1.1019x; 1.1019x over previous
//
#include <hip/hip_runtime.h>

// ApproxNDCGLoss, N=20000, fp32 — TWO dispatches; LDS scatter + coalesced out.
//
// R7 post-mortem: privatized hist/cursor = NULL (81.4 vs 80.8) => block-0
// sort is NOT LDS-atomic-bound. Remaining un-touched cost: the global
// scatter — 20k UNCOALESCED 4B stores to g_ybkt from ONE CU (~64 lines per
// wave-store => ~20k transactions through one VMEM pipe ≈ 8-10 us). Matches
// the R5/R6 arithmetic for the block-0 straggler.
//
// R8 change (only): scatter into LDS ybkt_l[20480] (80 KB; LDS eats random
// 4B scatter at bank speed), then copy out to g_ybkt COALESCED as float4
// (1250 line-aligned wave stores, ~16x fewer transactions). Per-bucket
// multiset identical => consume math byte-identical => absmax stays 0.0.
// R7's privatization reverted (proven neutral); single hist, LDS ~89 KB.
//
// Decision rule: if Δtotal < 2 us, kernel side is gap-dominated => structure
// floor (39.5 us unavoidable ws-poison fill + 2 minimal kernels + graph
// overhead) reached; declare roofline next round.

#define LOG2E 1.442695040888963387f
#define M_NODES 64
#define XHALF 8.0
#define NB 2048
#define PI_D 3.14159265358979323846
#define BT 1024
#define LDS_N 20480
#define MAXN 131072

#if __has_builtin(__builtin_amdgcn_exp2f)
#define EXP2(x) __builtin_amdgcn_exp2f(x)
#else
#define EXP2(x) exp2f(x)
#endif

#if __has_builtin(__builtin_amdgcn_rcpf)
#define RCP(x) __builtin_amdgcn_rcpf(x)
#else
#define RCP(x) (1.0f / (x))
#endif

// ---- module-global state (poison-free; visibility via kernel boundary) ----
__device__ double g_acc[3] = {0.0, 0.0, 0.0};  // dcg, idcg, ysum
__device__ int g_done = 0;
__device__ float2 g_nodes[M_NODES];  // (x_k, F_k)
__device__ int g_prefix[NB + 1];     // bucket starts
__device__ float g_ybkt[MAXN];       // bucket-sorted y

__device__ __forceinline__ int bucket_of(float y) {
  int b = (int)(y * (float)NB);
  return b < 0 ? 0 : (b > NB - 1 ? NB - 1 : b);
}

// ---- produce: blk 0 = sort (LDS scatter, coalesced out); blk 1..64 = nodes
__global__ __launch_bounds__(BT) void produce_kernel(
    const float* __restrict__ s, const float* __restrict__ y, int n) {
  const int tid = threadIdx.x;
  const int blk = blockIdx.x;
  const int lane = tid & 63;

  __shared__ int hist[NB];          // histogram, then scatter cursor (8 KB)
  __shared__ float ybkt_l[LDS_N];   // LDS scatter target (80 KB)
  __shared__ int wrep[16];          // scan wave partials
  __shared__ double wsum[16];       // node reduction scratch

  if (blk == 0) {
    // --- histogram ---
    for (int b = tid; b < NB; b += BT) hist[b] = 0;
    __syncthreads();

    const float4* y4 = (const float4*)y;
    const int n4 = n >> 2;
    for (int i = tid; i < n4; i += BT) {
      const float4 v = y4[i];
      atomicAdd(&hist[bucket_of(v.x)], 1);
      atomicAdd(&hist[bucket_of(v.y)], 1);
      atomicAdd(&hist[bucket_of(v.z)], 1);
      atomicAdd(&hist[bucket_of(v.w)], 1);
    }
    for (int i = (n4 << 2) + tid; i < n; i += BT)
      atomicAdd(&hist[bucket_of(y[i])], 1);
    __syncthreads();

    // --- exclusive scan (2 bins/thread), shuffle-based, 2 barriers ---
    const int base = tid * 2;
    const int l0 = hist[base], l1 = hist[base + 1];
    const int sum2 = l0 + l1;
    int v = sum2;
#pragma unroll
    for (int d = 1; d < 64; d <<= 1) {
      const int t = __shfl_up(v, d);
      if (lane >= d) v += t;
    }
    if (lane == 63) wrep[tid >> 6] = v;
    __syncthreads();
    if (tid < 16) {
      int wv = wrep[tid];
#pragma unroll
      for (int d = 1; d < 16; d <<= 1) {
        const int t = __shfl_up(wv, d);
        if (tid >= d) wv += t;
      }
      wrep[tid] = wv;
    }
    __syncthreads();
    const int wbase = (tid >> 6) ? wrep[(tid >> 6) - 1] : 0;
    const int incl = wbase + v;
    const int run = incl - sum2;  // exclusive prefix of this 2-bin chunk
    g_prefix[base] = run;         // publish (boundary makes it visible)
    g_prefix[base + 1] = run + l0;
    if (tid == BT - 1) g_prefix[NB] = incl;  // == n
    hist[base] = run;  // LDS scatter cursor
    hist[base + 1] = run + l0;
    __syncthreads();

    if (n <= LDS_N) {
      // --- scatter into LDS (random 4B writes at bank speed) ---
      for (int i = tid; i < n4; i += BT) {
        const float4 v4 = y4[i];
        ybkt_l[atomicAdd(&hist[bucket_of(v4.x)], 1)] = v4.x;
        ybkt_l[atomicAdd(&hist[bucket_of(v4.y)], 1)] = v4.y;
        ybkt_l[atomicAdd(&hist[bucket_of(v4.z)], 1)] = v4.z;
        ybkt_l[atomicAdd(&hist[bucket_of(v4.w)], 1)] = v4.w;
      }
      for (int i = (n4 << 2) + tid; i < n; i += BT) {
        const float yv = y[i];
        ybkt_l[atomicAdd(&hist[bucket_of(yv)], 1)] = yv;
      }
      __syncthreads();
      // --- coalesced copy-out: float4 line-aligned wave stores ---
      const int nv = (n + 3) >> 2;  // tail lanes copy unused LDS — harmless
      float4* gb4 = (float4*)g_ybkt;
      const float4* lb4 = (const float4*)ybkt_l;
      for (int i = tid; i < nv; i += BT) gb4[i] = lb4[i];
    } else {
      // fallback (n > LDS_N): direct global scatter as in R6
      for (int i = tid; i < n4; i += BT) {
        const float4 v4 = y4[i];
        g_ybkt[atomicAdd(&hist[bucket_of(v4.x)], 1)] = v4.x;
        g_ybkt[atomicAdd(&hist[bucket_of(v4.y)], 1)] = v4.y;
        g_ybkt[atomicAdd(&hist[bucket_of(v4.z)], 1)] = v4.z;
        g_ybkt[atomicAdd(&hist[bucket_of(v4.w)], 1)] = v4.w;
      }
      for (int i = (n4 << 2) + tid; i < n; i += BT) {
        const float yv = y[i];
        g_ybkt[atomicAdd(&hist[bucket_of(yv)], 1)] = yv;
      }
    }
  } else {
    // --- node k: F(x_k) = sum_i sigmoid(x_k - s_i) (verified math) ---
    const int k = blk - 1;
    const float xk =
        (float)(XHALF * cos(PI_D * (double)k / (double)(M_NODES - 1)));
    double F = 0.0;
    const float4* s4 = (const float4*)s;
    const int n4 = n >> 2;
    for (int i = tid; i < n4; i += BT) {
      const float4 v = s4[i];
      float t = RCP(1.0f + EXP2((v.x - xk) * LOG2E));
      t += RCP(1.0f + EXP2((v.y - xk) * LOG2E));
      t += RCP(1.0f + EXP2((v.z - xk) * LOG2E));
      t += RCP(1.0f + EXP2((v.w - xk) * LOG2E));
      F += (double)t;
    }
    for (int i = (n4 << 2) + tid; i < n; i += BT)
      F += (double)RCP(1.0f + EXP2((s[i] - xk) * LOG2E));
    for (int off = 32; off > 0; off >>= 1) F += __shfl_down(F, off);
    if (lane == 0) wsum[tid >> 6] = F;
    __syncthreads();
    if (tid == 0) {
      double t = 0.0;
#pragma unroll
      for (int w = 0; w < 16; ++w) t += wsum[w];
      g_nodes[k] = make_float2(xk, (float)t);
    }
  }
}

// ---- consume: barycentric dcg + parallel rank-scan idcg + finalize ----
__global__ __launch_bounds__(256) void consume_kernel(
    const float* __restrict__ s, const float* __restrict__ y,
    float* __restrict__ out, int n, int nblocks) {
  __shared__ float2 nd[M_NODES];
  __shared__ double wsum[12];
  const int tid = threadIdx.x;
  if (tid < M_NODES) nd[tid] = g_nodes[tid];
  __syncthreads();

  const int j = blockIdx.x * 256 + tid;
  double dc = 0.0, ic = 0.0, ys = 0.0;
  if (j < n) {
    const float x = s[j];
    const float yj = y[j];
    // dcg: barycentric interpolation of F(s_j) over 64 Chebyshev nodes
    double num = 0.0, den = 0.0;
    int hit = -1;
#pragma unroll
    for (int k = 0; k < M_NODES; ++k) {
      const float d = x - nd[k].x;
      float w = (k & 1) ? -1.0f : 1.0f;
      if (k == 0 || k == M_NODES - 1) w *= 0.5f;
      if (d == 0.0f) {
        hit = k;
      } else {
        const float iv = w * RCP(d);
        num += (double)iv * (double)nd[k].y;
        den += (double)iv;
      }
    }
    const double F = (hit >= 0) ? (double)nd[hit].y : (num / den);

    // idcg: exact rank = 1 + #(strictly greater); L2-resident bucket scan
    const int b = bucket_of(yj);
    const int s0 = g_prefix[b];
    const int s1 = g_prefix[b + 1];
    int cnt = n - s1;  // strictly higher buckets
    for (int t = s0; t < s1; ++t) cnt += (g_ybkt[t] > yj);

    dc = (double)yj / log2(F + 2.0);
    ic = (double)yj / log2((double)cnt + 2.0);
    ys = (double)yj;
  }
  for (int off = 32; off > 0; off >>= 1) {
    dc += __shfl_down(dc, off);
    ic += __shfl_down(ic, off);
    ys += __shfl_down(ys, off);
  }
  const int wv = tid >> 6;
  if ((tid & 63) == 0) {
    wsum[wv] = dc;
    wsum[wv + 4] = ic;
    wsum[wv + 8] = ys;
  }
  __syncthreads();
  if (tid == 0) {
    atomicAdd(&g_acc[0], wsum[0] + wsum[1] + wsum[2] + wsum[3]);
    atomicAdd(&g_acc[1], wsum[4] + wsum[5] + wsum[6] + wsum[7]);
    atomicAdd(&g_acc[2], wsum[8] + wsum[9] + wsum[10] + wsum[11]);
    __threadfence();
    const int old = atomicAdd(&g_done, 1);
    if (old == nblocks - 1) {  // last block: all acc updates visible
      const double dcg = atomicAdd(&g_acc[0], 0.0);
      const double idcg = atomicAdd(&g_acc[1], 0.0);
      const double ysum = atomicAdd(&g_acc[2], 0.0);
      const double loss = 1.0 - dcg / (idcg + 1e-8);
      out[0] = (ysum < 1.0) ? 0.0f : (float)loss;
      // self-clean for next replay (visible via kernel boundary)
      g_acc[0] = 0.0;
      g_acc[1] = 0.0;
      g_acc[2] = 0.0;
      g_done = 0;
      __threadfence();
    }
  }
}

extern "C" void kernel_launch(void* const* d_in, const int* in_sizes, int n_in,
                              void* d_out, int out_size, void* d_ws,
                              size_t ws_size, hipStream_t stream) {
  const float* s = (const float*)d_in[0];
  const float* y = (const float*)d_in[1];
  const int n = in_sizes[0];
  (void)d_ws;
  (void)ws_size;  // ws poison is unconditional; module globals are poison-free

  const int nb = (n + 255) / 256;
  produce_kernel<<<M_NODES + 1, BT, 0, stream>>>(s, y, n);
  consume_kernel<<<nb, 256, 0, stream>>>(s, y, (float*)d_out, n, nb);
}